// Round 9
// baseline (214.487 us; speedup 1.0000x reference)
//
#include <hip/hip_runtime.h>
#include <hip/hip_bf16.h>
#include <hip/hip_fp16.h>

// ---------------------------------------------------------------------------
// GCN 2-layer inference:
//   h1 = relu( D^-1/2 (A+I) D^-1/2 (x @ W1) + b1 )
//   out = softmax( D^-1/2 (A+I) D^-1/2 (h1 @ W2) + b2 )
//
// memset(bcur) -> bin -> count_b -> scan1/2/3 -> fill_b -> prepW ->
// gemm1_mfma (register-direct split-bf16 MFMA, 32 rows x 64 cols per wave,
// ping-pong B pipeline) -> agg1 -> gemm2 -> agg2.
//
// Round-8 lesson: 32 rows x 128 cols/wave shrank the grid to 391 blocks
// (1.5 blocks/CU, occupancy 13%) -> TLP-starved. Now each wave does
// 32 rows x 64 cols: grid 782 (3 blocks/CU), same total B traffic
// (400MB L2), same 3:1 MFMA:load ratio, ping-pong kept.
// ---------------------------------------------------------------------------

#define F_IN 512
#define NHID 128
#define NCLS 64
#define BSHIFT 8           // 256 nodes per bucket
#define CHUNK 4096         // edges per bin block

typedef __attribute__((ext_vector_type(8))) short short8;
typedef __attribute__((ext_vector_type(4))) float f32x4;

__device__ __forceinline__ unsigned f2u(float f) { union { float f; unsigned u; } v; v.f = f; return v.u; }
__device__ __forceinline__ float u2f(unsigned u) { union { unsigned u; float f; } v; v.u = u; return v.f; }

// ---------------- binning: LDS counting-sort of 4096-edge chunks by bucket ----------------

__global__ __launch_bounds__(256) void bin_kernel(const int* __restrict__ src,
        const int* __restrict__ dst, int2* __restrict__ pairs,
        int* __restrict__ bcur, int E, int cap) {
    __shared__ int lcnt[256];
    __shared__ int lscan[256];
    __shared__ int gbase[256];
    __shared__ int wsum[4];
    __shared__ int2 stage[CHUNK];
    const int t = threadIdx.x;
    const int lane = t & 63, wid = t >> 6;
    const int e0 = blockIdx.x * CHUNK;
    const int n = min(CHUNK, E - e0);

    lcnt[t] = 0;
    __syncthreads();
    for (int i = t; i < n; i += 256)
        atomicAdd(&lcnt[dst[e0 + i] >> BSHIFT], 1);
    __syncthreads();
    const int v = lcnt[t];
    int s = v;
    #pragma unroll
    for (int d = 1; d < 64; d <<= 1) {
        int tt = __shfl_up(s, d);
        if (lane >= d) s += tt;
    }
    if (lane == 63) wsum[wid] = s;
    __syncthreads();
    int woff = 0;
    for (int w = 0; w < wid; ++w) woff += wsum[w];
    lscan[t] = woff + s - v;
    gbase[t] = v ? atomicAdd(&bcur[t], v) : 0;
    lcnt[t] = 0;
    __syncthreads();
    for (int i = t; i < n; i += 256) {
        int d = dst[e0 + i], sc = src[e0 + i];
        int b = d >> BSHIFT;
        int p = atomicAdd(&lcnt[b], 1);
        stage[lscan[b] + p] = make_int2(d, sc);
    }
    __syncthreads();
    for (int i = t; i < n; i += 256) {
        int2 pr = stage[i];
        int b = pr.x >> BSHIFT;
        int off = gbase[b] + (i - lscan[b]);
        if (off < cap) pairs[(size_t)b * cap + off] = pr;
    }
}

// ---------------- per-bucket degree count (LDS histogram, dense cnt write) ----------------

__global__ __launch_bounds__(256) void count_b_kernel(const int2* __restrict__ pairs,
        const int* __restrict__ bcur, int* __restrict__ cnt, int cap) {
    __shared__ int hist[256];
    const int b = blockIdx.x;
    const int t = threadIdx.x;
    hist[t] = 0;
    __syncthreads();
    const int n = min(bcur[b], cap);
    const int2* p = pairs + (size_t)b * cap;
    for (int i = t; i < n; i += 256)
        atomicAdd(&hist[p[i].x & 255], 1);
    __syncthreads();
    cnt[(b << BSHIFT) + t] = hist[t];
}

// ---------------- row_ptr scan ----------------

__global__ __launch_bounds__(256) void scan1_kernel(const int* __restrict__ cnt,
        int* __restrict__ row_ptr, float* __restrict__ dinv,
        int* __restrict__ bsum, int N) {
    __shared__ int wsum[4];
    const int tid = threadIdx.x;
    const int lane = tid & 63, wid = tid >> 6;
    const int base = blockIdx.x * 1024 + tid * 4;
    int4 v = {0, 0, 0, 0};
    if (base + 3 < N) {
        v = *reinterpret_cast<const int4*>(&cnt[base]);
    } else {
        if (base + 0 < N) v.x = cnt[base + 0];
        if (base + 1 < N) v.y = cnt[base + 1];
        if (base + 2 < N) v.z = cnt[base + 2];
        if (base + 3 < N) v.w = cnt[base + 3];
    }
    if (base + 0 < N) dinv[base + 0] = rsqrtf((float)v.x + 1.0f);
    if (base + 1 < N) dinv[base + 1] = rsqrtf((float)v.y + 1.0f);
    if (base + 2 < N) dinv[base + 2] = rsqrtf((float)v.z + 1.0f);
    if (base + 3 < N) dinv[base + 3] = rsqrtf((float)v.w + 1.0f);
    const int tsum = v.x + v.y + v.z + v.w;
    int s = tsum;
    #pragma unroll
    for (int d = 1; d < 64; d <<= 1) {
        int t = __shfl_up(s, d);
        if (lane >= d) s += t;
    }
    if (lane == 63) wsum[wid] = s;
    __syncthreads();
    int woff = 0;
    for (int w = 0; w < wid; ++w) woff += wsum[w];
    const int excl = woff + s - tsum;
    if (base + 0 < N) row_ptr[base + 0] = excl;
    if (base + 1 < N) row_ptr[base + 1] = excl + v.x;
    if (base + 2 < N) row_ptr[base + 2] = excl + v.x + v.y;
    if (base + 3 < N) row_ptr[base + 3] = excl + v.x + v.y + v.z;
    if (tid == 255) bsum[blockIdx.x] = excl + tsum;
}

__global__ __launch_bounds__(64) void scan2_kernel(const int* __restrict__ bsum,
        int* __restrict__ boff, int* __restrict__ row_ptr, int nb, int N) {
    const int lane = threadIdx.x;
    int v = (lane < nb) ? bsum[lane] : 0;
    int s = v;
    #pragma unroll
    for (int d = 1; d < 64; d <<= 1) {
        int t = __shfl_up(s, d);
        if (lane >= d) s += t;
    }
    if (lane < nb) boff[lane] = s - v;
    if (lane == 63) row_ptr[N] = s;
}

__global__ void scan3_kernel(int* __restrict__ row_ptr, const int* __restrict__ boff, int N) {
    int i = blockIdx.x * blockDim.x + threadIdx.x;
    if (i < N) row_ptr[i] += boff[i >> 10];
}

// ---------------- CSR placement: LDS cursor, bucket-local col writes ----------------

__global__ __launch_bounds__(512) void fill_b_kernel(const int2* __restrict__ pairs,
        const int* __restrict__ bcur, const int* __restrict__ row_ptr,
        int* __restrict__ col, int cap) {
    __shared__ int lcur[256];
    const int b = blockIdx.x;
    const int t = threadIdx.x;
    if (t < 256) lcur[t] = 0;
    __syncthreads();
    const int n = min(bcur[b], cap);
    const int2* p = pairs + (size_t)b * cap;
    for (int i = t; i < n; i += 512) {
        int2 pr = p[i];
        int pos = row_ptr[pr.x] + atomicAdd(&lcur[pr.x & 255], 1);
        col[pos] = pr.y;
    }
}

// ---------------- prepW: W1 -> fragment-packed hi/lo bf16 ----------------
// Fragment f = ks*8 + nt. Lane l of frag f: cols nt*16+(l&15),
// k = ks*32+(l>>4)*8 .. +8. Stored at [f*512 + l*8] shorts.

__global__ __launch_bounds__(256) void prepW_kernel(const float* __restrict__ W1,
        short* __restrict__ Whp, short* __restrict__ Wlp) {
    const int g = blockIdx.x * 256 + threadIdx.x;  // 0..8191
    const int f = g >> 6;
    const int lane = g & 63;
    const int ks = f >> 3, nt = f & 7;
    const int colg = nt * 16 + (lane & 15);
    const int k0 = ks * 32 + (lane >> 4) * 8;
    short8 vh, vl;
    #pragma unroll
    for (int j = 0; j < 8; ++j) {
        float w = W1[(size_t)(k0 + j) * NHID + colg];
        unsigned u = f2u(w);
        vh[j] = (short)(u >> 16);
        float hif = u2f(u & 0xffff0000u);
        vl[j] = (short)(f2u(w - hif) >> 16);
    }
    *reinterpret_cast<short8*>(Whp + ((size_t)f << 9) + (lane << 3)) = vh;
    *reinterpret_cast<short8*>(Wlp + ((size_t)f << 9) + (lane << 3)) = vl;
}

// ---------------- GEMM1: 32 rows x 64 cols per wave, ping-pong B pipeline ----------------

__device__ __forceinline__ void cvt8(const float4& u0, const float4& u1,
                                     short8& h, short8& l) {
    float av[8] = {u0.x, u0.y, u0.z, u0.w, u1.x, u1.y, u1.z, u1.w};
    #pragma unroll
    for (int j = 0; j < 8; ++j) {
        unsigned u = f2u(av[j]);
        h[j] = (short)(u >> 16);
        float hif = u2f(u & 0xffff0000u);
        l[j] = (short)(f2u(av[j] - hif) >> 16);
    }
}

// load fragments for 2 consecutive ntiles (ntb, ntb+1) of K-step ks
#define LOADG(H0, L0, H1, L1, ks, ntb) { \
    const short* _p = Whp + (((size_t)((ks) * 8 + (ntb))) << 9) + (lane << 3); \
    const short* _q = Wlp + (((size_t)((ks) * 8 + (ntb))) << 9) + (lane << 3); \
    H0 = *reinterpret_cast<const short8*>(_p); \
    L0 = *reinterpret_cast<const short8*>(_q); \
    H1 = *reinterpret_cast<const short8*>(_p + 512); \
    L1 = *reinterpret_cast<const short8*>(_q + 512); }

// 12 MFMAs: 2 row-frags x 2 ntiles (local g -> acc cols 2g, 2g+1)
#define MFMAG(H0, L0, H1, L1, g) { \
    acc[0][2*(g)]   = __builtin_amdgcn_mfma_f32_16x16x32_bf16(ah0, H0, acc[0][2*(g)], 0, 0, 0); \
    acc[0][2*(g)]   = __builtin_amdgcn_mfma_f32_16x16x32_bf16(ah0, L0, acc[0][2*(g)], 0, 0, 0); \
    acc[0][2*(g)]   = __builtin_amdgcn_mfma_f32_16x16x32_bf16(al0, H0, acc[0][2*(g)], 0, 0, 0); \
    acc[0][2*(g)+1] = __builtin_amdgcn_mfma_f32_16x16x32_bf16(ah0, H1, acc[0][2*(g)+1], 0, 0, 0); \
    acc[0][2*(g)+1] = __builtin_amdgcn_mfma_f32_16x16x32_bf16(ah0, L1, acc[0][2*(g)+1], 0, 0, 0); \
    acc[0][2*(g)+1] = __builtin_amdgcn_mfma_f32_16x16x32_bf16(al0, L1 - L1 + H1, acc[0][2*(g)+1], 0, 0, 0); \
    acc[1][2*(g)]   = __builtin_amdgcn_mfma_f32_16x16x32_bf16(ah1, H0, acc[1][2*(g)], 0, 0, 0); \
    acc[1][2*(g)]   = __builtin_amdgcn_mfma_f32_16x16x32_bf16(ah1, L0, acc[1][2*(g)], 0, 0, 0); \
    acc[1][2*(g)]   = __builtin_amdgcn_mfma_f32_16x16x32_bf16(al1, H0, acc[1][2*(g)], 0, 0, 0); \
    acc[1][2*(g)+1] = __builtin_amdgcn_mfma_f32_16x16x32_bf16(ah1, H1, acc[1][2*(g)+1], 0, 0, 0); \
    acc[1][2*(g)+1] = __builtin_amdgcn_mfma_f32_16x16x32_bf16(ah1, L1, acc[1][2*(g)+1], 0, 0, 0); \
    acc[1][2*(g)+1] = __builtin_amdgcn_mfma_f32_16x16x32_bf16(al1, H1, acc[1][2*(g)+1], 0, 0, 0); }

__global__ __launch_bounds__(256, 3) void gemm1_mfma(
        const float* __restrict__ X, const short* __restrict__ Whp,
        const short* __restrict__ Wlp, const float* __restrict__ dinv,
        __half* __restrict__ Hs16, int M) {
    const int tid = threadIdx.x;
    const int lane = tid & 63;
    const int wid = tid >> 6;          // 0..3
    const int l15 = lane & 15;
    const int kc = lane >> 4;
    const int rbase = blockIdx.x * 64 + (wid >> 1) * 32;
    const int cg = wid & 1;            // column group: ntiles cg*4 .. +4

    int ar0 = rbase + l15;      if (ar0 > M - 1) ar0 = M - 1;
    int ar1 = rbase + 16 + l15; if (ar1 > M - 1) ar1 = M - 1;
    const float* xp0 = X + (size_t)ar0 * F_IN + kc * 8;
    const float* xp1 = X + (size_t)ar1 * F_IN + kc * 8;

    f32x4 acc[2][4];
    #pragma unroll
    for (int i = 0; i < 2; ++i)
        #pragma unroll
        for (int j = 0; j < 4; ++j)
            acc[i][j] = (f32x4){0.f, 0.f, 0.f, 0.f};

    short8 ah0, al0, ah1, al1;
    {
        float4 a00 = *reinterpret_cast<const float4*>(xp0);
        float4 a01 = *reinterpret_cast<const float4*>(xp0 + 4);
        float4 a10 = *reinterpret_cast<const float4*>(xp1);
        float4 a11 = *reinterpret_cast<const float4*>(xp1 + 4);
        cvt8(a00, a01, ah0, al0);
        cvt8(a10, a11, ah1, al1);
    }
    short8 p0h0, p0l0, p0h1, p0l1;   // ping: ntiles cg*4+0,1
    short8 p1h0, p1l0, p1h1, p1l1;   // pong: ntiles cg*4+2,3
    LOADG(p0h0, p0l0, p0h1, p0l1, 0, cg * 4);

    for (int ks = 0; ks < 16; ++ks) {
        const bool last = (ks == 15);
        float4 n00, n01, n10, n11;
        if (!last) {
            n00 = *reinterpret_cast<const float4*>(xp0 + (ks + 1) * 32);
            n01 = *reinterpret_cast<const float4*>(xp0 + (ks + 1) * 32 + 4);
            n10 = *reinterpret_cast<const float4*>(xp1 + (ks + 1) * 32);
            n11 = *reinterpret_cast<const float4*>(xp1 + (ks + 1) * 32 + 4);
        }
        LOADG(p1h0, p1l0, p1h1, p1l1, ks, cg * 4 + 2);
        MFMAG(p0h0, p0l0, p0h1, p0l1, 0);
        if (!last) LOADG(p0h0, p0l0, p0h1, p0l1, ks + 1, cg * 4);
        MFMAG(p1h0, p1l0, p1h1, p1l1, 1);
        if (!last) {
            cvt8(n00, n01, ah0, al0);
            cvt8(n10, n11, ah1, al1);
        }
    }

    #pragma unroll
    for (int rr = 0; rr < 2; ++rr) {
        #pragma unroll
        for (int r = 0; r < 4; ++r) {
            const int orow = rbase + rr * 16 + kc * 4 + r;
            if (orow < M) {
                const float di = dinv[orow];
                #pragma unroll
                for (int nt = 0; nt < 4; ++nt) {
                    Hs16[(size_t)orow * NHID + (cg * 4 + nt) * 16 + l15] =
                        __float2half(acc[rr][nt][r] * di);
                }
            }
        }
    }
}

// ---------------- AGG1: Y = relu(dinv[i]*(Hs[i] + sum Hs[src]) + b1) ----------------

__global__ __launch_bounds__(64) void agg1_kernel(const __half2* __restrict__ Hs,
        const int* __restrict__ row_ptr, const int* __restrict__ col,
        const float* __restrict__ dinv, const float* __restrict__ b1,
        float* __restrict__ Y) {
    const int i = blockIdx.x;
    const int c = threadIdx.x;           // col-pair 0..63
    const int beg = row_ptr[i], end = row_ptr[i + 1];
    float2 f = __half22float2(Hs[(size_t)i * 64 + c]);
    float ax = f.x, ay = f.y;
    int e = beg;
    for (; e + 8 <= end; e += 8) {
        float2 v[8];
        #pragma unroll
        for (int j = 0; j < 8; ++j) {
            int s = col[e + j];
            v[j] = __half22float2(Hs[(size_t)s * 64 + c]);
        }
        #pragma unroll
        for (int j = 0; j < 8; ++j) { ax += v[j].x; ay += v[j].y; }
    }
    for (; e < end; ++e) {
        float2 v = __half22float2(Hs[(size_t)col[e] * 64 + c]);
        ax += v.x; ay += v.y;
    }
    const float di = dinv[i];
    const float2 bb = reinterpret_cast<const float2*>(b1)[c];
    float2 o;
    o.x = fmaxf(fmaf(ax, di, bb.x), 0.0f);
    o.y = fmaxf(fmaf(ay, di, bb.y), 0.0f);
    *reinterpret_cast<float2*>(&Y[(size_t)i * NHID + 2 * c]) = o;
}

// ---------------- GEMM2: H2s16 = fp16((Y @ W2) * dinv[row])  [N,64] ----------------

__global__ __launch_bounds__(256) void gemm2_kernel(const float* __restrict__ Y,
        const float* __restrict__ W2, const float* __restrict__ dinv,
        __half* __restrict__ H2s16, int N) {
    __shared__ float Ws[NHID][NCLS];
    __shared__ float Ys[16][NHID];
    const int tid = threadIdx.x;
    const int i0 = blockIdx.x * 16;
    #pragma unroll
    for (int t = 0; t < 8; ++t) {
        int v = tid + t * 256;
        int k = v >> 4;
        int c4 = (v & 15) * 4;
        *reinterpret_cast<float4*>(&Ws[k][c4]) =
            *reinterpret_cast<const float4*>(&W2[(size_t)k * NCLS + c4]);
    }
    #pragma unroll
    for (int t = 0; t < 2; ++t) {
        int v = tid + t * 256;
        int r = v >> 5;
        int c4 = (v & 31) * 4;
        int gr = i0 + r; if (gr > N - 1) gr = N - 1;
        *reinterpret_cast<float4*>(&Ys[r][c4]) =
            *reinterpret_cast<const float4*>(&Y[(size_t)gr * NHID + c4]);
    }
    __syncthreads();
    const int c = tid & 63;
    const int rg = tid >> 6;
    float acc[4] = {0.f, 0.f, 0.f, 0.f};
    #pragma unroll 8
    for (int k = 0; k < NHID; ++k) {
        float w = Ws[k][c];
        #pragma unroll
        for (int j = 0; j < 4; ++j)
            acc[j] = fmaf(Ys[rg * 4 + j][k], w, acc[j]);
    }
    #pragma unroll
    for (int j = 0; j < 4; ++j) {
        int gr = i0 + rg * 4 + j;
        if (gr < N) H2s16[(size_t)gr * NCLS + c] = __float2half(acc[j] * dinv[gr]);
    }
}

// ---------------- AGG2 + softmax: two nodes per wave ----------------

__global__ __launch_bounds__(64) void agg2_kernel(const __half2* __restrict__ H2,
        const int* __restrict__ row_ptr, const int* __restrict__ col,
        const float* __restrict__ dinv, const float* __restrict__ b2,
        float* __restrict__ out, int N) {
    const int lane = threadIdx.x;
    const int node = blockIdx.x * 2 + (lane >> 5);
    const int c = lane & 31;             // col-pair 0..31
    if (node >= N) return;
    const int beg = row_ptr[node], end = row_ptr[node + 1];
    float2 f = __half22float2(H2[(size_t)node * 32 + c]);
    float ax = f.x, ay = f.y;
    int e = beg;
    for (; e + 8 <= end; e += 8) {
        float2 v[8];
        #pragma unroll
        for (int j = 0; j < 8; ++j) {
            int s = col[e + j];
            v[j] = __half22float2(H2[(size_t)s * 32 + c]);
        }
        #pragma unroll
        for (int j = 0; j < 8; ++j) { ax += v[j].x; ay += v[j].y; }
    }
    for (; e < end; ++e) {
        float2 v = __half22float2(H2[(size_t)col[e] * 32 + c]);
        ax += v.x; ay += v.y;
    }
    const float di = dinv[node];
    const float2 bb = reinterpret_cast<const float2*>(b2)[c];
    float vx = fmaf(ax, di, bb.x);
    float vy = fmaf(ay, di, bb.y);
    float m = fmaxf(vx, vy);
    #pragma unroll
    for (int d = 16; d >= 1; d >>= 1) m = fmaxf(m, __shfl_xor(m, d));
    float ex = __expf(vx - m), ey = __expf(vy - m);
    float sum = ex + ey;
    #pragma unroll
    for (int d = 16; d >= 1; d >>= 1) sum += __shfl_xor(sum, d);
    float2 o = {ex / sum, ey / sum};
    reinterpret_cast<float2*>(out)[(size_t)node * 32 + c] = o;
}

// ---------------- launch ----------------

extern "C" void kernel_launch(void* const* d_in, const int* in_sizes, int n_in,
                              void* d_out, int out_size, void* d_ws, size_t ws_size,
                              hipStream_t stream) {
    const float* x  = (const float*)d_in[0];
    const int*   ei = (const int*)d_in[1];
    const float* W1 = (const float*)d_in[2];
    const float* b1 = (const float*)d_in[3];
    const float* W2 = (const float*)d_in[4];
    const float* b2 = (const float*)d_in[5];
    const int N = in_sizes[0] / F_IN;
    const int E = in_sizes[1] / 2;
    const int* src = ei;
    const int* dst = ei + E;
    float* out = (float*)d_out;

    const int Npad  = (N + 63) & ~63;
    const int Nb256 = (N + 255) & ~255;           // cnt size (bucket-dense)
    const int Epad  = (E + 63) & ~63;
    int*    cnt     = (int*)d_ws;                 // Nb256
    int*    bcur    = cnt + Nb256;                // 256
    int*    row_ptr = bcur + 256;                 // Npad (>= N+1)
    float*  dinv    = (float*)(row_ptr + Npad);   // Npad
    int*    col     = (int*)(dinv + Npad);        // Epad
    int*    bsum    = col + Epad;                 // 64
    int*    boff    = bsum + 64;                  // 64
    __half* Hs16    = (__half*)(boff + 64);       // Npad*128 halfs (12.8MB)
    float*  Y       = (float*)(Hs16 + (size_t)Npad * NHID);  // Npad*128 f32 (25.6MB)
    __half* H2s16   = Hs16;                       // reuse (Hs dead after agg1)
    short*  Whp     = (short*)Y;                  // overlay Y start (128KB)
    short*  Wlp     = Whp + (size_t)F_IN * NHID;  // +128KB
    // bucket pair storage overlays Y at +512KB; dead before agg1 writes Y
    int2*   pairs   = (int2*)((char*)Y + 512 * 1024);

    const int nb = (N + 1023) / 1024;
    const int nbuck = (N + 255) >> BSHIFT;                  // 196
    const int cap = (((E / nbuck) * 3 / 2) + 63) & ~63;     // ~12288

    hipMemsetAsync(bcur, 0, 256 * sizeof(int), stream);
    bin_kernel<<<(E + CHUNK - 1) / CHUNK, 256, 0, stream>>>(src, dst, pairs, bcur, E, cap);
    count_b_kernel<<<nbuck, 256, 0, stream>>>(pairs, bcur, cnt, cap);
    scan1_kernel<<<nb, 256, 0, stream>>>(cnt, row_ptr, dinv, bsum, N);
    scan2_kernel<<<1, 64, 0, stream>>>(bsum, boff, row_ptr, nb, N);
    scan3_kernel<<<(N + 255) / 256, 256, 0, stream>>>(row_ptr, boff, N);
    fill_b_kernel<<<nbuck, 512, 0, stream>>>(pairs, bcur, row_ptr, col, cap);
    prepW_kernel<<<32, 256, 0, stream>>>(W1, Whp, Wlp);
    gemm1_mfma<<<(N + 63) / 64, 256, 0, stream>>>(x, Whp, Wlp, dinv, Hs16, N);
    agg1_kernel<<<N, 64, 0, stream>>>((const __half2*)Hs16, row_ptr, col, dinv, b1, Y);
    gemm2_kernel<<<(N + 15) / 16, 256, 0, stream>>>(Y, W2, dinv, H2s16, N);
    agg2_kernel<<<(N + 1) / 2, 64, 0, stream>>>((const __half2*)H2s16, row_ptr, col, dinv, b2, out, N);
}